// Round 3
// baseline (508.597 us; speedup 1.0000x reference)
//
#include <hip/hip_runtime.h>
#include <math.h>

#define EMB 1024
#define HEADS 16
#define DH 64
#define DFF 4096
#define NTOK 2048
#define BATCH 2
#define MROWS 4096

typedef __attribute__((ext_vector_type(8))) _Float16 f16x8;
typedef __attribute__((ext_vector_type(4))) float floatx4;

typedef const __attribute__((address_space(1))) void gas_void;
typedef __attribute__((address_space(3))) void las_void;

__device__ __forceinline__ unsigned short f2h(float f) {
    union { _Float16 h; unsigned short u; } c; c.h = (_Float16)f; return c.u;
}
__device__ __forceinline__ float h2f(unsigned short u) {
    union { _Float16 h; unsigned short u; } c; c.u = u; return (float)c.h;
}

// ---------------- bias concat fp32: [bq|bk|bv | b1 | b2] = 3072+4096+1024 ----
__global__ __launch_bounds__(256) void bias_prep(
    const float* __restrict__ bq, const float* __restrict__ bk,
    const float* __restrict__ bv, const float* __restrict__ b1,
    const float* __restrict__ b2, float* __restrict__ out)
{
    int i = blockIdx.x * 256 + threadIdx.x;
    float v;
    if (i < 1024)      v = bq[i];
    else if (i < 2048) v = bk[i - 1024];
    else if (i < 3072) v = bv[i - 2048];
    else if (i < 7168) v = b1[i - 3072];
    else               v = b2[i - 7168];
    out[i] = v;
}

// ---------------- transpose fp32 -> fp16: out[c][r] = in[r][c], 64x64 tiles ----
__global__ __launch_bounds__(256) void transpose_f2h(
    const float* __restrict__ in, int ld_in,
    unsigned short* __restrict__ out, int ld_out)
{
    __shared__ unsigned short tile[64][72];
    const int t = threadIdx.x;
    const int r0 = blockIdx.y * 64, c0 = blockIdx.x * 64;
    const int rr = t >> 4, c4 = (t & 15) * 4;
#pragma unroll
    for (int p = 0; p < 4; p++) {
        float4 v = *(const float4*)&in[(size_t)(r0 + rr + p * 16) * ld_in + c0 + c4];
        tile[rr + p * 16][c4 + 0] = f2h(v.x);
        tile[rr + p * 16][c4 + 1] = f2h(v.y);
        tile[rr + p * 16][c4 + 2] = f2h(v.z);
        tile[rr + p * 16][c4 + 3] = f2h(v.w);
    }
    __syncthreads();
#pragma unroll
    for (int p = 0; p < 4; p++) {
        const int c = rr + p * 16;
        ushort4 v;
        v.x = tile[c4 + 0][c]; v.y = tile[c4 + 1][c];
        v.z = tile[c4 + 2][c]; v.w = tile[c4 + 3][c];
        *(ushort4*)&out[(size_t)(c0 + c) * ld_out + r0 + c4] = v;
    }
}

// ---------------- V transpose (fp16): vT[bh][d][n] = qkv[b*NTOK+n][2048+h*64+d] ----
__global__ __launch_bounds__(256) void vtrans(
    const unsigned short* __restrict__ qkv, unsigned short* __restrict__ vT)
{
    __shared__ unsigned short tile[64][72];
    const int t = threadIdx.x;
    const int n0 = blockIdx.x * 64;
    const int bh = blockIdx.y;
    const int b = bh >> 4, h = bh & 15;
    const int rr = t >> 4, c4 = (t & 15) * 4;
    const unsigned short* src = qkv + (size_t)b * NTOK * 3072 + 2048 + h * 64;
#pragma unroll
    for (int p = 0; p < 4; p++) {
        ushort4 v = *(const ushort4*)&src[(size_t)(n0 + rr + p * 16) * 3072 + c4];
        *(ushort4*)&tile[rr + p * 16][c4] = v;
    }
    __syncthreads();
    unsigned short* dst = vT + (size_t)bh * 64 * NTOK;
#pragma unroll
    for (int p = 0; p < 4; p++) {
        const int d = rr + p * 16;
        ushort4 v;
        v.x = tile[c4 + 0][d]; v.y = tile[c4 + 1][d];
        v.z = tile[c4 + 2][d]; v.w = tile[c4 + 3][d];
        *(ushort4*)&dst[(size_t)d * NTOK + n0 + c4] = v;
    }
}

// ---------------- LayerNorm: fp32 in -> fp16 out, rows of 1024 ----
__global__ __launch_bounds__(256) void ln_kernel(
    const float* __restrict__ in,
    const float* __restrict__ g,
    const float* __restrict__ be,
    unsigned short* __restrict__ out)
{
    const int row = blockIdx.x, t = threadIdx.x;
    const size_t base = (size_t)row * 1024 + t * 4;
    float4 xv = *(const float4*)&in[base];
    float v0 = xv.x, v1 = xv.y, v2 = xv.z, v3 = xv.w;
    float s = v0 + v1 + v2 + v3;
    float q = v0 * v0 + v1 * v1 + v2 * v2 + v3 * v3;
#pragma unroll
    for (int m = 1; m < 64; m <<= 1) { s += __shfl_xor(s, m, 64); q += __shfl_xor(q, m, 64); }
    __shared__ float red[8];
    if ((t & 63) == 0) { red[t >> 6] = s; red[4 + (t >> 6)] = q; }
    __syncthreads();
    s = red[0] + red[1] + red[2] + red[3];
    q = red[4] + red[5] + red[6] + red[7];
    const float mu = s * (1.f / 1024.f);
    const float var = q * (1.f / 1024.f) - mu * mu;
    const float rs = rsqrtf(var + 1e-6f);
    float4 gv = *(const float4*)&g[t * 4];
    float4 bv = *(const float4*)&be[t * 4];
    ushort4 ov;
    ov.x = f2h((v0 - mu) * rs * gv.x + bv.x);
    ov.y = f2h((v1 - mu) * rs * gv.y + bv.y);
    ov.z = f2h((v2 - mu) * rs * gv.z + bv.z);
    ov.w = f2h((v3 - mu) * rs * gv.w + bv.w);
    *(ushort4*)&out[base] = ov;
}

// ---------------- GEMM: C = A[M][K] @ Bt[N][K]^T + bias, epilogue EPI ----
// EPI 0: fp16 store. 1: exact GELU, fp16 store. 2: + fp32 resid, fp32 store.
// 128x128 tile, BK=64, 4 waves (2x2), 4x4 16x16x32-MFMA frags/wave (m97 structure)
template<int EPI, typename CT>
__global__ __launch_bounds__(256) void gemm_f16(
    const unsigned short* __restrict__ A, int lda,
    const unsigned short* __restrict__ Bt, int ldb,
    const float* __restrict__ bias,
    const float* __restrict__ resid,
    CT* __restrict__ C, int ldc, int K)
{
    __shared__ unsigned short As[128 * 64];
    __shared__ unsigned short Bs[128 * 64];
    const int t = threadIdx.x;
    const int l = t & 63, w = t >> 6;
    const int wr = w >> 1, wc = w & 1;
    const int lr = l & 15, lg = l >> 4;
    const int m0 = blockIdx.y * 128, n0 = blockIdx.x * 128;

    const int srow = t >> 3;        // 0..31
    const int scol = (t & 7) * 8;   // 0..56
    const unsigned short* ga0 = A + (size_t)(m0 + srow) * lda + scol;
    const unsigned short* gb0 = Bt + (size_t)(n0 + srow) * ldb + scol;
    const int ldsbase = w * 512;    // element offset, wave-uniform

    floatx4 acc[4][4];
#pragma unroll
    for (int a = 0; a < 4; a++)
#pragma unroll
        for (int b = 0; b < 4; b++) acc[a][b] = (floatx4){0.f, 0.f, 0.f, 0.f};

    for (int k0 = 0; k0 < K; k0 += 64) {
#pragma unroll
        for (int i = 0; i < 4; i++)
            __builtin_amdgcn_global_load_lds((gas_void*)(ga0 + (size_t)i * 32 * lda + k0),
                                             (las_void*)(As + i * 2048 + ldsbase), 16, 0, 0);
#pragma unroll
        for (int i = 0; i < 4; i++)
            __builtin_amdgcn_global_load_lds((gas_void*)(gb0 + (size_t)i * 32 * ldb + k0),
                                             (las_void*)(Bs + i * 2048 + ldsbase), 16, 0, 0);
        __syncthreads();
#pragma unroll
        for (int kf = 0; kf < 2; kf++) {
            f16x8 af[4], bfr[4];
#pragma unroll
            for (int a = 0; a < 4; a++)
                af[a] = *(const f16x8*)&As[(wr * 64 + a * 16 + lr) * 64 + kf * 32 + lg * 8];
#pragma unroll
            for (int b = 0; b < 4; b++)
                bfr[b] = *(const f16x8*)&Bs[(wc * 64 + b * 16 + lr) * 64 + kf * 32 + lg * 8];
#pragma unroll
            for (int a = 0; a < 4; a++)
#pragma unroll
                for (int b = 0; b < 4; b++)
                    acc[a][b] = __builtin_amdgcn_mfma_f32_16x16x32_f16(af[a], bfr[b], acc[a][b], 0, 0, 0);
        }
        __syncthreads();
    }

#pragma unroll
    for (int a = 0; a < 4; a++) {
        const int row0 = m0 + wr * 64 + a * 16 + lg * 4;
#pragma unroll
        for (int b = 0; b < 4; b++) {
            const int col = n0 + wc * 64 + b * 16 + lr;
            const float bs = bias[col];
#pragma unroll
            for (int r = 0; r < 4; r++) {
                float v = acc[a][b][r] + bs;
                if (EPI == 1) v = 0.5f * v * (1.0f + erff(v * 0.70710678118654752f));
                const size_t idx = (size_t)(row0 + r) * ldc + col;
                if (EPI == 2) v += resid[idx];
                if (sizeof(CT) == 2) C[idx] = (CT)f2h(v);
                else                 C[idx] = (CT)v;
            }
        }
    }
}

// ---------------- Flash attention (no 1/sqrt(dh) scale!), residual fused ----
// grid (16 qblocks, 32 bh); 4 waves x 32 q-rows; KV tile = 32 keys.
__global__ __launch_bounds__(256) void attn_kernel(
    const unsigned short* __restrict__ qkv,
    const unsigned short* __restrict__ vT,
    const float* __restrict__ x,
    float* __restrict__ y)
{
    __shared__ unsigned short P[4][32 * 32];
    const int t = threadIdx.x;
    const int l = t & 63, w = t >> 6;
    const int lr = l & 15, lg = l >> 4;
    const int qb = blockIdx.x, bh = blockIdx.y;
    const int b = bh >> 4, h = bh & 15;
    const int q0 = qb * 128 + w * 32;

    const unsigned short* qbase = qkv + (size_t)b * NTOK * 3072 + h * 64;
    const unsigned short* kbase = qbase + 1024;
    const unsigned short* vbase = vT + (size_t)bh * 64 * NTOK;

    f16x8 qf[2][2];
#pragma unroll
    for (int mf = 0; mf < 2; mf++)
#pragma unroll
        for (int kf = 0; kf < 2; kf++)
            qf[mf][kf] = *(const f16x8*)&qbase[(size_t)(q0 + mf * 16 + lr) * 3072 + kf * 32 + lg * 8];

    floatx4 o[2][4];
    float mrun[2][4], lrun[2][4];
#pragma unroll
    for (int mf = 0; mf < 2; mf++) {
#pragma unroll
        for (int df = 0; df < 4; df++) o[mf][df] = (floatx4){0.f, 0.f, 0.f, 0.f};
#pragma unroll
        for (int r = 0; r < 4; r++) { mrun[mf][r] = -1e30f; lrun[mf][r] = 0.f; }
    }

    for (int kt = 0; kt < NTOK; kt += 32) {
        f16x8 kfr[2][2];
#pragma unroll
        for (int n = 0; n < 2; n++)
#pragma unroll
            for (int kf = 0; kf < 2; kf++)
                kfr[n][kf] = *(const f16x8*)&kbase[(size_t)(kt + n * 16 + lr) * 3072 + kf * 32 + lg * 8];

        floatx4 s[2][2];
#pragma unroll
        for (int mf = 0; mf < 2; mf++)
#pragma unroll
            for (int n = 0; n < 2; n++) {
                s[mf][n] = (floatx4){0.f, 0.f, 0.f, 0.f};
                s[mf][n] = __builtin_amdgcn_mfma_f32_16x16x32_f16(qf[mf][0], kfr[n][0], s[mf][n], 0, 0, 0);
                s[mf][n] = __builtin_amdgcn_mfma_f32_16x16x32_f16(qf[mf][1], kfr[n][1], s[mf][n], 0, 0, 0);
            }

        // online softmax; row = mf*16 + lg*4 + r, cols = n*16 + lr
#pragma unroll
        for (int mf = 0; mf < 2; mf++) {
#pragma unroll
            for (int r = 0; r < 4; r++) {
                float a0 = s[mf][0][r], a1 = s[mf][1][r];
                float tm = fmaxf(a0, a1);
#pragma unroll
                for (int msk = 1; msk < 16; msk <<= 1) tm = fmaxf(tm, __shfl_xor(tm, msk, 64));
                const float nm = fmaxf(mrun[mf][r], tm);
                const float corr = __expf(mrun[mf][r] - nm);
                mrun[mf][r] = nm;
                const float p0 = __expf(a0 - nm);
                const float p1 = __expf(a1 - nm);
                float rs = p0 + p1;
#pragma unroll
                for (int msk = 1; msk < 16; msk <<= 1) rs += __shfl_xor(rs, msk, 64);
                lrun[mf][r] = lrun[mf][r] * corr + rs;
#pragma unroll
                for (int df = 0; df < 4; df++) o[mf][df][r] *= corr;
                P[w][(mf * 16 + lg * 4 + r) * 32 + lr]      = f2h(p0);
                P[w][(mf * 16 + lg * 4 + r) * 32 + 16 + lr] = f2h(p1);
            }
        }

        // PV: A = P (rows lane-mapped), B = vT (k = key contiguous)
        f16x8 pa[2];
#pragma unroll
        for (int mf = 0; mf < 2; mf++)
            pa[mf] = *(const f16x8*)&P[w][(mf * 16 + lr) * 32 + lg * 8];
        f16x8 vf[4];
#pragma unroll
        for (int df = 0; df < 4; df++)
            vf[df] = *(const f16x8*)&vbase[(size_t)(df * 16 + lr) * NTOK + kt + lg * 8];
#pragma unroll
        for (int mf = 0; mf < 2; mf++)
#pragma unroll
            for (int df = 0; df < 4; df++)
                o[mf][df] = __builtin_amdgcn_mfma_f32_16x16x32_f16(pa[mf], vf[df], o[mf][df], 0, 0, 0);
    }

    // epilogue: normalize, add fp32 residual x, write fp32 y
#pragma unroll
    for (int mf = 0; mf < 2; mf++)
#pragma unroll
        for (int r = 0; r < 4; r++) {
            const float inv = 1.0f / lrun[mf][r];
            const int row = q0 + mf * 16 + lg * 4 + r;
#pragma unroll
            for (int df = 0; df < 4; df++) {
                const size_t idx = (size_t)(b * NTOK + row) * 1024 + h * 64 + df * 16 + lr;
                y[idx] = o[mf][df][r] * inv + x[idx];
            }
        }
}

extern "C" void kernel_launch(void* const* d_in, const int* in_sizes, int n_in,
                              void* d_out, int out_size, void* d_ws, size_t ws_size,
                              hipStream_t stream)
{
    const float* x   = (const float*)d_in[0];
    const float* Wq  = (const float*)d_in[1];
    const float* bq  = (const float*)d_in[2];
    const float* Wk  = (const float*)d_in[3];
    const float* bk  = (const float*)d_in[4];
    const float* Wv  = (const float*)d_in[5];
    const float* bv  = (const float*)d_in[6];
    const float* g1  = (const float*)d_in[7];
    const float* be1 = (const float*)d_in[8];
    const float* g2  = (const float*)d_in[9];
    const float* be2 = (const float*)d_in[10];
    const float* W1  = (const float*)d_in[11];
    const float* b1  = (const float*)d_in[12];
    const float* W2  = (const float*)d_in[13];
    const float* b2  = (const float*)d_in[14];

    char* ws = (char*)d_ws;
    unsigned short* WqkvT = (unsigned short*)ws;  ws += (size_t)3072 * 1024 * 2;
    unsigned short* W1T   = (unsigned short*)ws;  ws += (size_t)4096 * 1024 * 2;
    unsigned short* W2T   = (unsigned short*)ws;  ws += (size_t)1024 * 4096 * 2;
    float*          biasf = (float*)ws;           ws += (size_t)8192 * 4;
    unsigned short* h1    = (unsigned short*)ws;  ws += (size_t)MROWS * 1024 * 2;  // reused as h2
    unsigned short* qkv   = (unsigned short*)ws;  ws += (size_t)MROWS * 3072 * 2;
    unsigned short* vT    = (unsigned short*)ws;  ws += (size_t)32 * 64 * NTOK * 2;
    float*          y     = (float*)ws;           ws += (size_t)MROWS * 1024 * 4;
    unsigned short* act1  = (unsigned short*)ws;  ws += (size_t)MROWS * 4096 * 2;
    unsigned short* h2    = h1;  // h1 dead after QKV gemm

    bias_prep<<<32, 256, 0, stream>>>(bq, bk, bv, b1, b2, biasf);
    transpose_f2h<<<dim3(16, 16), 256, 0, stream>>>(Wq, 1024, WqkvT, 1024);
    transpose_f2h<<<dim3(16, 16), 256, 0, stream>>>(Wk, 1024, WqkvT + 1024 * 1024, 1024);
    transpose_f2h<<<dim3(16, 16), 256, 0, stream>>>(Wv, 1024, WqkvT + 2 * 1024 * 1024, 1024);
    transpose_f2h<<<dim3(64, 16), 256, 0, stream>>>(W1, 4096, W1T, 1024);
    transpose_f2h<<<dim3(16, 64), 256, 0, stream>>>(W2, 1024, W2T, 4096);

    ln_kernel<<<MROWS, 256, 0, stream>>>(x, g1, be1, h1);
    gemm_f16<0, unsigned short><<<dim3(24, 32), 256, 0, stream>>>(h1, 1024, WqkvT, 1024, biasf, nullptr, qkv, 3072, 1024);
    vtrans<<<dim3(32, 32), 256, 0, stream>>>(qkv, vT);
    attn_kernel<<<dim3(16, 32), 256, 0, stream>>>(qkv, vT, x, y);
    ln_kernel<<<MROWS, 256, 0, stream>>>(y, g2, be2, h2);
    gemm_f16<1, unsigned short><<<dim3(32, 32), 256, 0, stream>>>(h2, 1024, W1T, 1024, biasf + 3072, nullptr, act1, 4096, 1024);
    gemm_f16<2, float><<<dim3(8, 32), 256, 0, stream>>>(act1, 4096, W2T, 4096, biasf + 7168, y, (float*)d_out, 1024, 4096);
}